// Round 4
// baseline (900.106 us; speedup 1.0000x reference)
//
#include <hip/hip_runtime.h>
#include <math.h>

// Problem constants (from reference setup_inputs)
constexpr int B   = 2;
constexpr int P   = 19248;
constexpr int N   = 100;   // TOP_K_CONF
constexpr int K   = 20;    // TOP_K_IOU
constexpr int HP  = 138;   // proto H/W
constexpr int HPP = HP * HP;
constexpr int H   = 550;
constexpr int W   = 550;
constexpr int DM  = 32;    // mask dim
constexpr float EPS = 1e-6f;
constexpr int NBIN = 2048;      // histogram bins over sign-mapped d bits >> 21
constexpr int CAND = 2048;      // candidate cap (expected ~400/batch with margin)
constexpr int NPAIR = N * (N - 1) / 2;  // 4950
constexpr int HW = H * W;

constexpr int GRID = 256;       // one block per CU -> all blocks co-resident
constexpr int TPB  = 1024;      // 16 waves/block -> 4 waves/SIMD
constexpr int WPB  = TPB / 64;  // waves per block
constexpr int CHUNK = (HW + GRID - 1) / GRID;  // 1182 output px per block

// ---- global workspace (4-byte words). Atomic-only region [0,513); normal
// stores start at word 1024. Total 84 KB (proven ws is far larger).
constexpr int OFS_GMAX = 0;       // uint [B*N]  col-max bits (atomicMax only)
constexpr int OFS_BAR  = 512;     // uint        barrier ticket (atomic only)
constexpr int OFS_IOU  = 1024;    // float [B,N,N] upper-tri (normal stores)

// ---- LDS: persistent block-local results + phase-sequenced union
struct alignas(16) Persist {
  float sconf[B][N];        // top-100 scores
  float sloc[B][N][4];      // top-100 boxes
  int   sidx[B][N];         // top-100 original indices
  float kl[B][K][4];        // kept boxes
  float kc[B][K];           // kept scores
  float km[B][K][DM];       // kept mask coeffs
};
struct SmemA { int h[B][NBIN]; int c[B][NBIN / 16]; int T[B]; };
struct SmemC { float cv[B][CAND]; int ci[B][CAND]; int cnt[B]; };
struct SmemE { unsigned int mb[B][N]; int keepL[B][K]; float coefL[B][K];
               float red[WPB]; };
struct SmemF { float sfc[B][4][HP]; float red[WPB]; };
union  SmemU { SmemA a; SmemC c; SmemE e; SmemF f; };
// union 32.8 KB + persist 10.7 KB = 43.5 KB static LDS (1 block/CU)

// Grid barrier, ockl-style: RELAXED spin (no per-iteration cache invalidate),
// one release fence before the ticket, one acquire fence after exit.
__device__ __forceinline__ void gridbar(unsigned int* bar) {
  __syncthreads();
  if (threadIdx.x == 0) {
    __threadfence();               // release
    unsigned int tk = __hip_atomic_fetch_add(bar, 1u, __ATOMIC_RELAXED,
                                             __HIP_MEMORY_SCOPE_AGENT);
    unsigned int target = (tk / (unsigned)GRID + 1u) * (unsigned)GRID;
    long long guard = 0;
    while (__hip_atomic_load(bar, __ATOMIC_RELAXED,
                             __HIP_MEMORY_SCOPE_AGENT) < target) {
      __builtin_amdgcn_s_sleep(4);
      if (++guard > (50LL << 20)) break;   // never hit legitimately
    }
    __threadfence();               // acquire
  }
  __syncthreads();
}

__device__ __forceinline__ float sig1(float cx, float cy) {
  float m  = fmaxf(cx, cy);
  float e0 = expf(cx - m), e1 = expf(cy - m);
  return e1 / (e0 + e1);           // bit-identical to all prior rounds
}

// monotone map: float bits -> unsigned, order-preserving over all reals
__device__ __forceinline__ unsigned dmap(float d) {
  unsigned u = __float_as_uint(d);
  return u ^ (unsigned)(((int)u >> 31) | 0x80000000);
}

__global__ __launch_bounds__(TPB, 1) void k_fused(
    const float* __restrict__ original, const float* __restrict__ loc,
    const float* __restrict__ conf, const float* __restrict__ mask,
    const float* __restrict__ proto, float* wsf, unsigned int* wsu,
    float* out) {
  const int t   = threadIdx.x;
  const int bid = blockIdx.x;
  unsigned int* bar = &wsu[OFS_BAR];
  __shared__ Persist ps;
  __shared__ SmemU sm;

  if (bid == 0 && t < 2)
    __hip_atomic_store(out + t, 0.0f, __ATOMIC_RELAXED,
                       __HIP_MEMORY_SCOPE_AGENT);

  // ============ Phase A (block-redundant): d = c1-c0 -> LDS histogram =======
  // v = sigmoid(d) is strictly monotone in d, so thresholding on d's
  // sign-mapped bits selects the same top region; sigmoid computed later
  // (bit-identically) only for candidates.
  {
    int* hh = &sm.a.h[0][0];
    for (int q = t; q < B * NBIN; q += TPB) hh[q] = 0;
  }
  __syncthreads();
  const float4* c4 = (const float4*)conf;
  constexpr int NQ4 = B * P / 2;   // two conf pairs per float4 (P even)
  for (int q = t; q < NQ4; q += TPB) {
    float4 c = c4[q];
    int bb = (q >= P / 2) ? 1 : 0;
    atomicAdd(&sm.a.h[bb][dmap(c.y - c.x) >> 21], 1);
    atomicAdd(&sm.a.h[bb][dmap(c.w - c.z) >> 21], 1);
  }
  __syncthreads();
  // threshold: smallest bin with cumulative-from-top >= N, widened by 16 bins
  // (conservative superset; exact (v,idx) rank later restores exact top-100)
  for (int b = 0; b < B; b++) {
    if (t < NBIN / 16) {
      int s = 0;
      for (int u = 0; u < 16; u++) s += sm.a.h[b][t * 16 + u];
      sm.a.c[b][t] = s;
    }
  }
  __syncthreads();
  if (t < B) {
    const int b = t;
    int acc = 0, ch = NBIN / 16 - 1;
    for (; ch >= 0; ch--) { int cs = sm.a.c[b][ch]; if (acc + cs >= N) break; acc += cs; }
    int T = 0;
    if (ch >= 0) {
      int bin = ch * 16 + 15;
      for (; bin >= ch * 16; bin--) { acc += sm.a.h[b][bin]; if (acc >= N) break; }
      T = bin;
    }
    sm.a.T[b] = max(T - 16, 0);   // safety margin against exact-v ties
  }
  __syncthreads();
  const int T0 = sm.a.T[0], T1 = sm.a.T[1];
  __syncthreads();   // all reads of sm.a done before union reuse

  // ============ Phase B (block-redundant): compact candidates to LDS ========
  if (t < B) sm.c.cnt[t] = 0;
  __syncthreads();
  for (int q = t; q < NQ4; q += TPB) {
    float4 c = c4[q];
    int bb = (q >= P / 2) ? 1 : 0;
    const int Tb = bb ? T1 : T0;
    if ((int)(dmap(c.y - c.x) >> 21) >= Tb) {
      int pos = atomicAdd(&sm.c.cnt[bb], 1);
      if (pos < CAND) {
        sm.c.cv[bb][pos] = sig1(c.x, c.y);   // exact sigmoid, candidates only
        sm.c.ci[bb][pos] = 2 * q - bb * P;
      }
    }
    if ((int)(dmap(c.w - c.z) >> 21) >= Tb) {
      int pos = atomicAdd(&sm.c.cnt[bb], 1);
      if (pos < CAND) {
        sm.c.cv[bb][pos] = sig1(c.z, c.w);
        sm.c.ci[bb][pos] = 2 * q + 1 - bb * P;
      }
    }
  }
  __syncthreads();

  // ============ Phase C (block-redundant): rank-based stable top-N ==========
  for (int b = 0; b < B; b++) {
    const int M = min(sm.c.cnt[b], CAND);
    for (int c = t; c < M; c += TPB) {
      float mv = sm.c.cv[b][c]; int mi = sm.c.ci[b][c];
      int rank = 0;
      for (int j2 = 0; j2 < M; j2++) {
        float jv = sm.c.cv[b][j2]; int ji = sm.c.ci[b][j2];
        rank += (jv > mv || (jv == mv && ji < mi)) ? 1 : 0;  // val desc, idx asc
      }
      if (rank < N) { ps.sconf[b][rank] = mv; ps.sidx[b][rank] = mi; }
    }
  }
  __syncthreads();
  for (int q = t; q < B * N * 4; q += TPB) {
    int b = q / (N * 4), rr = q - b * N * 4, k = rr >> 2, d = rr & 3;
    ps.sloc[b][k][d] = loc[((size_t)(b * P + ps.sidx[b][k])) * 4 + d];
  }
  __syncthreads();

  // ============ Phase D (grid-partitioned): gaussian IoU, 1 pair/wave =======
  // Reduction tree bit-identical to the proven 256-thread kernel.
  {
    const int wid  = bid * WPB + (t >> 6);   // 4096 waves
    const int lane = t & 63;
    for (int pr = wid; pr < B * NPAIR; pr += GRID * WPB) {
      const int b = (pr >= NPAIR) ? 1 : 0;
      const int r = pr - b * NPAIR;
      int i = (int)((199.0f - sqrtf((float)(39601 - 8 * r))) * 0.5f);
      i = min(max(i, 0), N - 2);
      while (i < N - 2 && ((i + 1) * (2 * N - 2 - i)) / 2 <= r) i++;
      while (i > 0 && (i * (2 * N - 1 - i)) / 2 > r) i--;
      const int j = i + 1 + (r - (i * (2 * N - 1 - i)) / 2);

      const float4 li = *(const float4*)&ps.sloc[b][i][0];
      const float4 lj = *(const float4*)&ps.sloc[b][j][0];

      float smn[4], ssi[4], ssj[4];
#pragma unroll
      for (int w4 = 0; w4 < 4; w4++) {
        smn[w4] = 0.0f; ssi[w4] = 0.0f; ssj[w4] = 0.0f;
#pragma unroll
        for (int q = 0; q < 4; q++) {
          int pix = lane + (w4 << 6) + (q << 8);
          int y = pix >> 5, x = pix & 31;
          float xs = (x + 0.5f) / 32.0f, ys = (y + 0.5f) / 32.0f;
          float dxi = (xs - li.x) / (li.z + 1e-4f);
          float dyi = (ys - li.y) / (li.w + 1e-4f);
          float gi = expf(-0.5f * (dxi * dxi + dyi * dyi));
          float dxj = (xs - lj.x) / (lj.z + 1e-4f);
          float dyj = (ys - lj.y) / (lj.w + 1e-4f);
          float gj = expf(-0.5f * (dxj * dxj + dyj * dyj));
          smn[w4] += fminf(gi, gj);
          ssi[w4] += gi;
          ssj[w4] += gj;
        }
      }
#pragma unroll
      for (int off = 32; off > 0; off >>= 1) {
#pragma unroll
        for (int w4 = 0; w4 < 4; w4++) {
          smn[w4] += __shfl_down(smn[w4], off);
          ssi[w4] += __shfl_down(ssi[w4], off);
          ssj[w4] += __shfl_down(ssj[w4], off);
        }
      }
      if (lane == 0) {
        float inter = smn[0] + smn[1] + smn[2] + smn[3];
        float si    = ssi[0] + ssi[1] + ssi[2] + ssi[3];
        float sj    = ssj[0] + ssj[1] + ssj[2] + ssj[3];
        float iou   = inter / (si + sj - inter);
        wsf[OFS_IOU + (b * N + i) * N + j] = iou;
        atomicMax(&wsu[OFS_GMAX + b * N + j], __float_as_uint(iou));
      }
    }
  }

  gridbar(bar);   // the ONLY grid barrier

  // ============ Phase E (block-redundant): NMS select + gathers ============
  {
    unsigned int* mbf = &sm.e.mb[0][0];
    for (int q = t; q < B * N; q += TPB) mbf[q] = wsu[OFS_GMAX + q];
  }
  __syncthreads();
  if (t < B * N) {
    int b = t / N, col = t - b * N;
    unsigned int vb = sm.e.mb[b][col];
    int rank = 0;
    for (int j2 = 0; j2 < N; j2++) {
      unsigned int jb = sm.e.mb[b][j2];
      rank += (jb < vb || (jb == vb && j2 < col)) ? 1 : 0;   // val asc, idx asc
    }
    if (rank < K) sm.e.keepL[b][rank] = col;
  }
  __syncthreads();
  if (t < B * K) {
    int b = t / K, k = t - b * K;
    int r = sm.e.keepL[b][k];
    float c = ps.sconf[b][r];
    ps.kc[b][k] = c;
    float l0 = ps.sloc[b][r][0], l1 = ps.sloc[b][r][1];
    float l2 = ps.sloc[b][r][2], l3 = ps.sloc[b][r][3];
    sm.e.coefL[b][k] = 0.25f * (l0 * l0 + l1 * l1 + l2 * l2 + l3 * l3) * c;
  }
  if (t < B * K * 4) {
    int b = t / (K * 4), rr = t - b * K * 4, k = rr >> 2, d = rr & 3;
    ps.kl[b][k][d] = ps.sloc[b][sm.e.keepL[b][k]][d];
  }
  for (int q = t; q < B * K * DM; q += TPB) {
    int b = q / (K * DM), rr = q - b * K * DM, k = rr >> 5, d = rr & 31;
    int orig = ps.sidx[b][sm.e.keepL[b][k]];
    ps.km[b][k][d] = mask[((size_t)(b * P + orig)) * DM + d];
  }
  __syncthreads();
  // ae loss: blocks 0,1 only (they have identical keep/coef as everyone)
  if (bid < B) {
    const int b = bid;
    float acc = 0.0f;
    for (int kc2 = t; kc2 < K * N; kc2 += TPB) {
      int k = kc2 / N, c = kc2 - k * N;
      int r = sm.e.keepL[b][k];
      if (c > r)
        acc += wsf[OFS_IOU + (b * N + r) * N + c] * ps.sconf[b][c] *
               sm.e.coefL[b][k];
    }
    for (int off = 32; off > 0; off >>= 1) acc += __shfl_down(acc, off);
    if ((t & 63) == 0) sm.e.red[t >> 6] = acc;
    __syncthreads();
    if (t == 0) {
      float s = 0.0f;
      for (int w2 = 0; w2 < WPB; w2++) s += sm.e.red[w2];
      atomicAdd(out + 1, s * (1.0f / (float)(B * N * N)));
    }
  }
  __syncthreads();   // sm.e dead before union reuse

  // ============ Phase F (tiled): final_conf rows this block needs, in LDS ====
  const int p0 = bid * CHUNK;
  const int p1 = min(p0 + CHUNK, HW);
  const int h0 = p0 / W, h1 = (p1 - 1) / W;
  const float scl = 138.0f / 550.0f;
  const int ylo = max(0, (int)floorf((h0 + 0.5f) * scl - 0.5f));
  const int yhi = min(HP - 1, (int)floorf((h1 + 0.5f) * scl - 0.5f) + 1);
  const int nrows = yhi - ylo + 1;   // <= 3 (alloc 4)
  for (int idx = t; idx < B * nrows * HP; idx += TPB) {
    int b  = idx / (nrows * HP);
    int rr = idx - b * nrows * HP;
    int ry = rr / HP, xx = rr - ry * HP;
    int yy = ylo + ry;
    float pv[DM];
    const float4* pp = (const float4*)&proto[(size_t)(b * HPP + yy * HP + xx) * DM];
#pragma unroll
    for (int q = 0; q < DM / 4; q++) {
      float4 f4 = pp[q];
      pv[q * 4 + 0] = f4.x; pv[q * 4 + 1] = f4.y;
      pv[q * 4 + 2] = f4.z; pv[q * 4 + 3] = f4.w;
    }
    const float ysv = (yy + 0.5f) / 138.0f;
    const float xsv = (xx + 0.5f) / 138.0f;
    float sum1 = 0.0f, sum2 = 0.0f;
#pragma unroll
    for (int k = 0; k < K; k++) {
      float dot = 0.0f;
#pragma unroll
      for (int d = 0; d < DM; d++) dot += pv[d] * ps.km[b][k][d];
      float a  = 1.0f / (1.0f + expf(-dot));
      float dx = (xsv - ps.kl[b][k][0]) / (ps.kl[b][k][2] + 1e-4f);
      float dy = (ysv - ps.kl[b][k][1]) / (ps.kl[b][k][3] + 1e-4f);
      float ug = expf(-0.5f * (dx * dx + dy * dy));
      float att = a * ug * ps.kc[b][k];
      sum1 += att;
      sum2 += att * att;
    }
    float fc = 1.0f - sum2 / (sum1 + EPS);
    if (fc != fc) fc = 0.0f;
    sm.f.sfc[b][ry][xx] = fc;
  }
  __syncthreads();

  // ============ Phase G: bilinear upsample + weighted variance ============
  {
    float acc = 0.0f;
    for (int pix = p0 + t; pix < p1; pix += TPB) {
      const int h = pix / W, w2 = pix - h * W;
      float sy = (h + 0.5f) * scl - 0.5f;
      float sx = (w2 + 0.5f) * scl - 0.5f;
      float fy0 = floorf(sy), fx0 = floorf(sx);
      float wy = sy - fy0, wx = sx - fx0;
      int y0 = max(0, (int)fy0), y1 = min(HP - 1, (int)fy0 + 1);
      int x0 = max(0, (int)fx0), x1 = min(HP - 1, (int)fx0 + 1);
      int ry0 = y0 - ylo, ry1 = y1 - ylo;
      float r0, r1;
      {
        float v00 = sm.f.sfc[0][ry0][x0], v01 = sm.f.sfc[0][ry0][x1];
        float v10 = sm.f.sfc[0][ry1][x0], v11 = sm.f.sfc[0][ry1][x1];
        float top = v00 + (v01 - v00) * wx;
        float bot = v10 + (v11 - v10) * wx;
        r0 = top + (bot - top) * wy;
      }
      {
        float v00 = sm.f.sfc[1][ry0][x0], v01 = sm.f.sfc[1][ry0][x1];
        float v10 = sm.f.sfc[1][ry1][x0], v11 = sm.f.sfc[1][ry1][x1];
        float top = v00 + (v01 - v00) * wx;
        float bot = v10 + (v11 - v10) * wx;
        r1 = top + (bot - top) * wy;
      }
      float total = r0 + r1;
      float inv_t  = 1.0f / total;           // wmean divides by total (no eps)
      float inv_te = 1.0f / (total + EPS);   // wvar divides by total+eps
#pragma unroll
      for (int c = 0; c < 3; c++) {
        float o0 = original[((0 * 3 + c) * H + h) * W + w2];
        float o1 = original[((1 * 3 + c) * H + h) * W + w2];
        float wm = (o0 * r0 + o1 * r1) * inv_t;
        float d0 = o0 - wm, d1 = o1 - wm;
        acc += (d0 * d0 * r0 + d1 * d1 * r1) * inv_te;
      }
    }
    for (int off = 32; off > 0; off >>= 1) acc += __shfl_down(acc, off);
    if ((t & 63) == 0) sm.f.red[t >> 6] = acc;
    __syncthreads();
    if (t == 0) {
      float s = 0.0f;
      for (int w3 = 0; w3 < WPB; w3++) s += sm.f.red[w3];
      atomicAdd(out + 0, s * ((float)B / (float)HP));
    }
  }
}

// ---------------------------------------------------------------------------
extern "C" void kernel_launch(void* const* d_in, const int* in_sizes, int n_in,
                              void* d_out, int out_size, void* d_ws,
                              size_t ws_size, hipStream_t stream) {
  (void)in_sizes; (void)n_in; (void)out_size; (void)ws_size;
  const float* original = (const float*)d_in[0];
  const float* loc      = (const float*)d_in[1];
  const float* conf     = (const float*)d_in[2];
  const float* mask     = (const float*)d_in[3];
  const float* proto    = (const float*)d_in[4];
  float* out = (float*)d_out;
  float* wsf = (float*)d_ws;
  unsigned int* wsu = (unsigned int*)d_ws;

  // zero gmax + barrier ticket (atomic-only region, words [0, 513))
  hipMemsetAsync(d_ws, 0, (size_t)(OFS_BAR + 1) * 4, stream);

  k_fused<<<GRID, TPB, 0, stream>>>(original, loc, conf, mask, proto,
                                    wsf, wsu, out);
}

// Round 5
// 226.126 us; speedup vs baseline: 3.9806x; 3.9806x over previous
//
#include <hip/hip_runtime.h>
#include <math.h>

// Problem constants (from reference setup_inputs)
constexpr int B   = 2;
constexpr int P   = 19248;
constexpr int N   = 100;   // TOP_K_CONF
constexpr int K   = 20;    // TOP_K_IOU
constexpr int HP  = 138;   // proto H/W
constexpr int HPP = HP * HP;
constexpr int H   = 550;
constexpr int W   = 550;
constexpr int DM  = 32;    // mask dim
constexpr float EPS = 1e-6f;
constexpr int NBIN = 2048;      // histogram bins over sign-mapped d bits >> 21
constexpr int CAND = 2048;      // candidate cap (expected ~330/batch, 6x margin)
constexpr int NPAIR = N * (N - 1) / 2;  // 4950
constexpr int HW = H * W;

constexpr int GRID = 256;       // one block per CU -> all blocks co-resident
constexpr int TPB  = 1024;      // 16 waves/block -> 4 waves/SIMD
constexpr int WPB  = TPB / 64;  // waves per block
constexpr int CHUNK = (HW + GRID - 1) / GRID;  // 1182 output px per block

// ---- global workspace (4-byte words). Atomic-only region [0,513); normal
// stores start at word 1024. Total 84 KB (proven ws is far larger).
constexpr int OFS_GMAX = 0;       // uint [B*N]  col-max bits (atomicMax only)
constexpr int OFS_BAR  = 512;     // uint        barrier ticket (atomic only)
constexpr int OFS_IOU  = 1024;    // float [B,N,N] upper-tri (normal stores)

// ---- LDS: persistent block-local results + phase-sequenced union
struct alignas(16) Persist {
  float sconf[B][N];        // top-100 scores
  float sloc[B][N][4];      // top-100 boxes
  int   sidx[B][N];         // top-100 original indices
  float kl[B][K][4];        // kept boxes
  float kc[B][K];           // kept scores
  float km[B][K][DM];       // kept mask coeffs
};
struct SmemA { int h[B][NBIN]; int c[B][NBIN / 16]; int T[B]; };
struct SmemC { float cv[B][CAND]; int ci[B][CAND]; int cnt[B]; };
struct SmemE { unsigned int mb[B][N]; int keepL[B][K]; float coefL[B][K];
               float red[WPB]; };
struct SmemF { float sfc[B][4][HP]; float red[WPB]; };
union  SmemU { SmemA a; SmemC c; SmemE e; SmemF f; };
// union 32.8 KB + persist 10.7 KB = 43.5 KB static LDS (1 block/CU)

// Grid barrier, ockl-style: RELAXED spin (no per-iteration cache invalidate),
// one release fence before the ticket, one acquire fence after exit.
__device__ __forceinline__ void gridbar(unsigned int* bar) {
  __syncthreads();
  if (threadIdx.x == 0) {
    __threadfence();               // release
    unsigned int tk = __hip_atomic_fetch_add(bar, 1u, __ATOMIC_RELAXED,
                                             __HIP_MEMORY_SCOPE_AGENT);
    unsigned int target = (tk / (unsigned)GRID + 1u) * (unsigned)GRID;
    long long guard = 0;
    while (__hip_atomic_load(bar, __ATOMIC_RELAXED,
                             __HIP_MEMORY_SCOPE_AGENT) < target) {
      __builtin_amdgcn_s_sleep(4);
      if (++guard > (50LL << 20)) break;   // never hit legitimately
    }
    __threadfence();               // acquire
  }
  __syncthreads();
}

__device__ __forceinline__ float sig1(float cx, float cy) {
  float m  = fmaxf(cx, cy);
  float e0 = expf(cx - m), e1 = expf(cy - m);
  return e1 / (e0 + e1);           // bit-identical to all prior rounds
}

// monotone map: float bits -> unsigned, order-preserving over all reals
__device__ __forceinline__ unsigned dmap(float d) {
  unsigned u = __float_as_uint(d);
  return u ^ (unsigned)(((int)u >> 31) | 0x80000000);
}

__global__ __launch_bounds__(TPB, 1) void k_fused(
    const float* __restrict__ original, const float* __restrict__ loc,
    const float* __restrict__ conf, const float* __restrict__ mask,
    const float* __restrict__ proto, float* wsf, unsigned int* wsu,
    float* out) {
  const int t   = threadIdx.x;
  const int bid = blockIdx.x;
  unsigned int* bar = &wsu[OFS_BAR];
  __shared__ Persist ps;
  __shared__ SmemU sm;

  if (bid == 0 && t < 2)
    __hip_atomic_store(out + t, 0.0f, __ATOMIC_RELAXED,
                       __HIP_MEMORY_SCOPE_AGENT);

  // ============ Phase A (block-redundant): d = c1-c0 -> LDS histogram =======
  // v = sigmoid(d) is strictly monotone in d, so thresholding on d's
  // sign-mapped bits selects the same top region; sigmoid computed later
  // (bit-identically) only for candidates.
  {
    int* hh = &sm.a.h[0][0];
    for (int q = t; q < B * NBIN; q += TPB) hh[q] = 0;
  }
  __syncthreads();
  const float4* c4 = (const float4*)conf;
  constexpr int NQ4 = B * P / 2;   // two conf pairs per float4 (P even)
  for (int q = t; q < NQ4; q += TPB) {
    float4 c = c4[q];
    int bb = (q >= P / 2) ? 1 : 0;
    atomicAdd(&sm.a.h[bb][dmap(c.y - c.x) >> 21], 1);
    atomicAdd(&sm.a.h[bb][dmap(c.w - c.z) >> 21], 1);
  }
  __syncthreads();
  // threshold: smallest bin with cumulative-from-top >= N, widened by ONE bin.
  // (1 bin suffices: a v-tie interval mapped to d-space is orders of magnitude
  //  narrower than any bin at the threshold, so it straddles <= 1 boundary.
  //  16-bin widening in r4 = /16 in d -> M~8400 -> CAND overflow + O(M^2) blowup.)
  for (int b = 0; b < B; b++) {
    if (t < NBIN / 16) {
      int s = 0;
      for (int u = 0; u < 16; u++) s += sm.a.h[b][t * 16 + u];
      sm.a.c[b][t] = s;
    }
  }
  __syncthreads();
  if (t < B) {
    const int b = t;
    int acc = 0, ch = NBIN / 16 - 1;
    for (; ch >= 0; ch--) { int cs = sm.a.c[b][ch]; if (acc + cs >= N) break; acc += cs; }
    int T = 0;
    if (ch >= 0) {
      int bin = ch * 16 + 15;
      for (; bin >= ch * 16; bin--) { acc += sm.a.h[b][bin]; if (acc >= N) break; }
      T = bin;
    }
    sm.a.T[b] = max(T - 1, 0);   // ONE-bin safety margin (the r4 bug was -16)
  }
  __syncthreads();
  const int T0 = sm.a.T[0], T1 = sm.a.T[1];
  __syncthreads();   // all reads of sm.a done before union reuse

  // ============ Phase B (block-redundant): compact candidates to LDS ========
  if (t < B) sm.c.cnt[t] = 0;
  __syncthreads();
  for (int q = t; q < NQ4; q += TPB) {
    float4 c = c4[q];
    int bb = (q >= P / 2) ? 1 : 0;
    const int Tb = bb ? T1 : T0;
    if ((int)(dmap(c.y - c.x) >> 21) >= Tb) {
      int pos = atomicAdd(&sm.c.cnt[bb], 1);
      if (pos < CAND) {
        sm.c.cv[bb][pos] = sig1(c.x, c.y);   // exact sigmoid, candidates only
        sm.c.ci[bb][pos] = 2 * q - bb * P;
      }
    }
    if ((int)(dmap(c.w - c.z) >> 21) >= Tb) {
      int pos = atomicAdd(&sm.c.cnt[bb], 1);
      if (pos < CAND) {
        sm.c.cv[bb][pos] = sig1(c.z, c.w);
        sm.c.ci[bb][pos] = 2 * q + 1 - bb * P;
      }
    }
  }
  __syncthreads();

  // ============ Phase C (block-redundant): rank-based stable top-N ==========
  for (int b = 0; b < B; b++) {
    const int M = min(sm.c.cnt[b], CAND);
    for (int c = t; c < M; c += TPB) {
      float mv = sm.c.cv[b][c]; int mi = sm.c.ci[b][c];
      int rank = 0;
      for (int j2 = 0; j2 < M; j2++) {
        float jv = sm.c.cv[b][j2]; int ji = sm.c.ci[b][j2];
        rank += (jv > mv || (jv == mv && ji < mi)) ? 1 : 0;  // val desc, idx asc
      }
      if (rank < N) { ps.sconf[b][rank] = mv; ps.sidx[b][rank] = mi; }
    }
  }
  __syncthreads();
  for (int q = t; q < B * N * 4; q += TPB) {
    int b = q / (N * 4), rr = q - b * N * 4, k = rr >> 2, d = rr & 3;
    ps.sloc[b][k][d] = loc[((size_t)(b * P + ps.sidx[b][k])) * 4 + d];
  }
  __syncthreads();

  // ============ Phase D (grid-partitioned): gaussian IoU, 1 pair/wave =======
  // Reduction tree bit-identical to the proven 256-thread kernel.
  {
    const int wid  = bid * WPB + (t >> 6);   // 4096 waves
    const int lane = t & 63;
    for (int pr = wid; pr < B * NPAIR; pr += GRID * WPB) {
      const int b = (pr >= NPAIR) ? 1 : 0;
      const int r = pr - b * NPAIR;
      int i = (int)((199.0f - sqrtf((float)(39601 - 8 * r))) * 0.5f);
      i = min(max(i, 0), N - 2);
      while (i < N - 2 && ((i + 1) * (2 * N - 2 - i)) / 2 <= r) i++;
      while (i > 0 && (i * (2 * N - 1 - i)) / 2 > r) i--;
      const int j = i + 1 + (r - (i * (2 * N - 1 - i)) / 2);

      const float4 li = *(const float4*)&ps.sloc[b][i][0];
      const float4 lj = *(const float4*)&ps.sloc[b][j][0];

      float smn[4], ssi[4], ssj[4];
#pragma unroll
      for (int w4 = 0; w4 < 4; w4++) {
        smn[w4] = 0.0f; ssi[w4] = 0.0f; ssj[w4] = 0.0f;
#pragma unroll
        for (int q = 0; q < 4; q++) {
          int pix = lane + (w4 << 6) + (q << 8);
          int y = pix >> 5, x = pix & 31;
          float xs = (x + 0.5f) / 32.0f, ys = (y + 0.5f) / 32.0f;
          float dxi = (xs - li.x) / (li.z + 1e-4f);
          float dyi = (ys - li.y) / (li.w + 1e-4f);
          float gi = expf(-0.5f * (dxi * dxi + dyi * dyi));
          float dxj = (xs - lj.x) / (lj.z + 1e-4f);
          float dyj = (ys - lj.y) / (lj.w + 1e-4f);
          float gj = expf(-0.5f * (dxj * dxj + dyj * dyj));
          smn[w4] += fminf(gi, gj);
          ssi[w4] += gi;
          ssj[w4] += gj;
        }
      }
#pragma unroll
      for (int off = 32; off > 0; off >>= 1) {
#pragma unroll
        for (int w4 = 0; w4 < 4; w4++) {
          smn[w4] += __shfl_down(smn[w4], off);
          ssi[w4] += __shfl_down(ssi[w4], off);
          ssj[w4] += __shfl_down(ssj[w4], off);
        }
      }
      if (lane == 0) {
        float inter = smn[0] + smn[1] + smn[2] + smn[3];
        float si    = ssi[0] + ssi[1] + ssi[2] + ssi[3];
        float sj    = ssj[0] + ssj[1] + ssj[2] + ssj[3];
        float iou   = inter / (si + sj - inter);
        wsf[OFS_IOU + (b * N + i) * N + j] = iou;
        atomicMax(&wsu[OFS_GMAX + b * N + j], __float_as_uint(iou));
      }
    }
  }

  gridbar(bar);   // the ONLY grid barrier

  // ============ Phase E (block-redundant): NMS select + gathers ============
  {
    unsigned int* mbf = &sm.e.mb[0][0];
    for (int q = t; q < B * N; q += TPB) mbf[q] = wsu[OFS_GMAX + q];
  }
  __syncthreads();
  if (t < B * N) {
    int b = t / N, col = t - b * N;
    unsigned int vb = sm.e.mb[b][col];
    int rank = 0;
    for (int j2 = 0; j2 < N; j2++) {
      unsigned int jb = sm.e.mb[b][j2];
      rank += (jb < vb || (jb == vb && j2 < col)) ? 1 : 0;   // val asc, idx asc
    }
    if (rank < K) sm.e.keepL[b][rank] = col;
  }
  __syncthreads();
  if (t < B * K) {
    int b = t / K, k = t - b * K;
    int r = sm.e.keepL[b][k];
    float c = ps.sconf[b][r];
    ps.kc[b][k] = c;
    float l0 = ps.sloc[b][r][0], l1 = ps.sloc[b][r][1];
    float l2 = ps.sloc[b][r][2], l3 = ps.sloc[b][r][3];
    sm.e.coefL[b][k] = 0.25f * (l0 * l0 + l1 * l1 + l2 * l2 + l3 * l3) * c;
  }
  if (t < B * K * 4) {
    int b = t / (K * 4), rr = t - b * K * 4, k = rr >> 2, d = rr & 3;
    ps.kl[b][k][d] = ps.sloc[b][sm.e.keepL[b][k]][d];
  }
  for (int q = t; q < B * K * DM; q += TPB) {
    int b = q / (K * DM), rr = q - b * K * DM, k = rr >> 5, d = rr & 31;
    int orig = ps.sidx[b][sm.e.keepL[b][k]];
    ps.km[b][k][d] = mask[((size_t)(b * P + orig)) * DM + d];
  }
  __syncthreads();
  // ae loss: blocks 0,1 only (they have identical keep/coef as everyone)
  if (bid < B) {
    const int b = bid;
    float acc = 0.0f;
    for (int kc2 = t; kc2 < K * N; kc2 += TPB) {
      int k = kc2 / N, c = kc2 - k * N;
      int r = sm.e.keepL[b][k];
      if (c > r)
        acc += wsf[OFS_IOU + (b * N + r) * N + c] * ps.sconf[b][c] *
               sm.e.coefL[b][k];
    }
    for (int off = 32; off > 0; off >>= 1) acc += __shfl_down(acc, off);
    if ((t & 63) == 0) sm.e.red[t >> 6] = acc;
    __syncthreads();
    if (t == 0) {
      float s = 0.0f;
      for (int w2 = 0; w2 < WPB; w2++) s += sm.e.red[w2];
      atomicAdd(out + 1, s * (1.0f / (float)(B * N * N)));
    }
  }
  __syncthreads();   // sm.e dead before union reuse

  // ============ Phase F (tiled): final_conf rows this block needs, in LDS ====
  const int p0 = bid * CHUNK;
  const int p1 = min(p0 + CHUNK, HW);
  const int h0 = p0 / W, h1 = (p1 - 1) / W;
  const float scl = 138.0f / 550.0f;
  const int ylo = max(0, (int)floorf((h0 + 0.5f) * scl - 0.5f));
  const int yhi = min(HP - 1, (int)floorf((h1 + 0.5f) * scl - 0.5f) + 1);
  const int nrows = yhi - ylo + 1;   // <= 3 (alloc 4)
  for (int idx = t; idx < B * nrows * HP; idx += TPB) {
    int b  = idx / (nrows * HP);
    int rr = idx - b * nrows * HP;
    int ry = rr / HP, xx = rr - ry * HP;
    int yy = ylo + ry;
    float pv[DM];
    const float4* pp = (const float4*)&proto[(size_t)(b * HPP + yy * HP + xx) * DM];
#pragma unroll
    for (int q = 0; q < DM / 4; q++) {
      float4 f4 = pp[q];
      pv[q * 4 + 0] = f4.x; pv[q * 4 + 1] = f4.y;
      pv[q * 4 + 2] = f4.z; pv[q * 4 + 3] = f4.w;
    }
    const float ysv = (yy + 0.5f) / 138.0f;
    const float xsv = (xx + 0.5f) / 138.0f;
    float sum1 = 0.0f, sum2 = 0.0f;
#pragma unroll
    for (int k = 0; k < K; k++) {
      float dot = 0.0f;
#pragma unroll
      for (int d = 0; d < DM; d++) dot += pv[d] * ps.km[b][k][d];
      float a  = 1.0f / (1.0f + expf(-dot));
      float dx = (xsv - ps.kl[b][k][0]) / (ps.kl[b][k][2] + 1e-4f);
      float dy = (ysv - ps.kl[b][k][1]) / (ps.kl[b][k][3] + 1e-4f);
      float ug = expf(-0.5f * (dx * dx + dy * dy));
      float att = a * ug * ps.kc[b][k];
      sum1 += att;
      sum2 += att * att;
    }
    float fc = 1.0f - sum2 / (sum1 + EPS);
    if (fc != fc) fc = 0.0f;
    sm.f.sfc[b][ry][xx] = fc;
  }
  __syncthreads();

  // ============ Phase G: bilinear upsample + weighted variance ============
  {
    float acc = 0.0f;
    for (int pix = p0 + t; pix < p1; pix += TPB) {
      const int h = pix / W, w2 = pix - h * W;
      float sy = (h + 0.5f) * scl - 0.5f;
      float sx = (w2 + 0.5f) * scl - 0.5f;
      float fy0 = floorf(sy), fx0 = floorf(sx);
      float wy = sy - fy0, wx = sx - fx0;
      int y0 = max(0, (int)fy0), y1 = min(HP - 1, (int)fy0 + 1);
      int x0 = max(0, (int)fx0), x1 = min(HP - 1, (int)fx0 + 1);
      int ry0 = y0 - ylo, ry1 = y1 - ylo;
      float r0, r1;
      {
        float v00 = sm.f.sfc[0][ry0][x0], v01 = sm.f.sfc[0][ry0][x1];
        float v10 = sm.f.sfc[0][ry1][x0], v11 = sm.f.sfc[0][ry1][x1];
        float top = v00 + (v01 - v00) * wx;
        float bot = v10 + (v11 - v10) * wx;
        r0 = top + (bot - top) * wy;
      }
      {
        float v00 = sm.f.sfc[1][ry0][x0], v01 = sm.f.sfc[1][ry0][x1];
        float v10 = sm.f.sfc[1][ry1][x0], v11 = sm.f.sfc[1][ry1][x1];
        float top = v00 + (v01 - v00) * wx;
        float bot = v10 + (v11 - v10) * wx;
        r1 = top + (bot - top) * wy;
      }
      float total = r0 + r1;
      float inv_t  = 1.0f / total;           // wmean divides by total (no eps)
      float inv_te = 1.0f / (total + EPS);   // wvar divides by total+eps
#pragma unroll
      for (int c = 0; c < 3; c++) {
        float o0 = original[((0 * 3 + c) * H + h) * W + w2];
        float o1 = original[((1 * 3 + c) * H + h) * W + w2];
        float wm = (o0 * r0 + o1 * r1) * inv_t;
        float d0 = o0 - wm, d1 = o1 - wm;
        acc += (d0 * d0 * r0 + d1 * d1 * r1) * inv_te;
      }
    }
    for (int off = 32; off > 0; off >>= 1) acc += __shfl_down(acc, off);
    if ((t & 63) == 0) sm.f.red[t >> 6] = acc;
    __syncthreads();
    if (t == 0) {
      float s = 0.0f;
      for (int w3 = 0; w3 < WPB; w3++) s += sm.f.red[w3];
      atomicAdd(out + 0, s * ((float)B / (float)HP));
    }
  }
}

// ---------------------------------------------------------------------------
extern "C" void kernel_launch(void* const* d_in, const int* in_sizes, int n_in,
                              void* d_out, int out_size, void* d_ws,
                              size_t ws_size, hipStream_t stream) {
  (void)in_sizes; (void)n_in; (void)out_size; (void)ws_size;
  const float* original = (const float*)d_in[0];
  const float* loc      = (const float*)d_in[1];
  const float* conf     = (const float*)d_in[2];
  const float* mask     = (const float*)d_in[3];
  const float* proto    = (const float*)d_in[4];
  float* out = (float*)d_out;
  float* wsf = (float*)d_ws;
  unsigned int* wsu = (unsigned int*)d_ws;

  // zero gmax + barrier ticket (atomic-only region, words [0, 513))
  hipMemsetAsync(d_ws, 0, (size_t)(OFS_BAR + 1) * 4, stream);

  k_fused<<<GRID, TPB, 0, stream>>>(original, loc, conf, mask, proto,
                                    wsf, wsu, out);
}